// Round 7
// baseline (446.042 us; speedup 1.0000x reference)
//
#include <hip/hip_runtime.h>

#define N_NODES 8192
#define IN_F 256
#define OUT_F 128
#define ALPHA 0.5f
#define JC 8
#define KCHUNK 1024            // N_NODES / JC
#define ROUNDS 32              // KCHUNK / 32

using short8 = __attribute__((ext_vector_type(8))) short;
using f32x4  = __attribute__((ext_vector_type(4))) float;

__device__ __forceinline__ unsigned int f2bf(float f){
  unsigned int u = __float_as_uint(f);
  u += 0x7fffu + ((u >> 16) & 1u);   // RNE
  return u >> 16;
}

// ---------------- K_hfp: fused h = x@W, f1/f2, pack P (bf16 frag-major) ----
// grid 256 x 256 thr; block = 32 rows = one P kb-block. h lives in registers;
// never hits HBM.
__global__ __launch_bounds__(256) void k_hfp(const float* __restrict__ x,
                                             const float* __restrict__ W,
                                             const float* __restrict__ a,
                                             float* __restrict__ f1,
                                             float* __restrict__ f2,
                                             unsigned short* __restrict__ P){
  __shared__ float xs[32*IN_F];          // 32 KB
  __shared__ unsigned short hl[32*136];  // 8.5 KB padded bf16 h tile
  const int tid = threadIdx.x;
  const int r0 = blockIdx.x * 32;
  const float4* xg = (const float4*)(x + (size_t)r0*IN_F);
  #pragma unroll
  for(int i=0;i<8;i++) ((float4*)xs)[tid + i*256] = xg[tid + i*256];
  __syncthreads();
  const int wave = tid >> 6, lane = tid & 63;
  float2 acc[8];
  #pragma unroll
  for(int j=0;j<8;j++){ acc[j].x = 0.f; acc[j].y = 0.f; }
  const float2* Wp = (const float2*)W;       // col pair 2l,2l+1 at k*64+lane
  for(int k4=0;k4<IN_F;k4+=4){
    float4 xq[8];
    #pragma unroll
    for(int j=0;j<8;j++) xq[j] = *(const float4*)&xs[(wave*8+j)*IN_F + k4];
    #pragma unroll
    for(int kk=0;kk<4;kk++){
      float2 wv = Wp[(size_t)(k4+kk)*64 + lane];
      #pragma unroll
      for(int j=0;j<8;j++){
        float xv = kk==0?xq[j].x : kk==1?xq[j].y : kk==2?xq[j].z : xq[j].w;
        acc[j].x += xv*wv.x; acc[j].y += xv*wv.y;
      }
    }
  }
  // f1/f2: per-row dot with a1/a2, shuffle-reduced across the wave
  {
    float2 a1 = ((const float2*)a)[lane];
    float2 a2 = ((const float2*)(a + OUT_F))[lane];
    float s1[8], s2[8];
    #pragma unroll
    for(int j=0;j<8;j++){
      s1[j] = acc[j].x*a1.x + acc[j].y*a1.y;
      s2[j] = acc[j].x*a2.x + acc[j].y*a2.y;
    }
    #pragma unroll
    for(int off=32; off; off>>=1){
      #pragma unroll
      for(int j=0;j<8;j++){
        s1[j] += __shfl_down(s1[j], off);
        s2[j] += __shfl_down(s2[j], off);
      }
    }
    if(lane == 0){
      #pragma unroll
      for(int j=0;j<8;j++){
        f1[r0 + wave*8 + j] = s1[j];
        f2[r0 + wave*8 + j] = s2[j];
      }
    }
  }
  // pack: bf16(h) -> LDS tile -> fragment-major P
  #pragma unroll
  for(int j=0;j<8;j++){
    unsigned int u = f2bf(acc[j].x) | (f2bf(acc[j].y) << 16);
    *(unsigned int*)&hl[(wave*8+j)*136 + 2*lane] = u;
  }
  __syncthreads();
  #pragma unroll
  for(int i=0;i<2;i++){
    int o = tid*2 + i;
    int c = o >> 6, ln = o & 63;
    int q = ln >> 4, n = ln & 15;
    short8 v;
    #pragma unroll
    for(int t=0;t<8;t++) v[t] = (short)hl[(q*8+t)*136 + c*16 + n];
    *(short8*)(P + ((size_t)(blockIdx.x*8 + c)*64 + ln)*8) = v;
  }
}

// ---------------- K_comp: adj (268MB) -> bitmask (8MB), linear stream ------
__global__ __launch_bounds__(256) void k_comp(const int* __restrict__ adj,
                                              unsigned long long* __restrict__ bm){
  const int lane = threadIdx.x & 63;
  const int wid = (blockIdx.x*256 + threadIdx.x) >> 6;
  const int nw = (gridDim.x*256) >> 6;
  const size_t total = (size_t)N_NODES*N_NODES;
  for(size_t base = (size_t)wid*512; base < total; base += (size_t)nw*512){
    unsigned long long msk[8];
    #pragma unroll
    for(int u=0;u<8;u++){
      int v = adj[base + (size_t)u*64 + lane];
      msk[u] = __ballot(v > 0);
    }
    if(lane < 8){
      unsigned long long v = msk[0];
      #pragma unroll
      for(int u=1;u<8;u++) v = (lane == u) ? msk[u] : v;
      bm[base/64 + lane] = v;
    }
  }
}

// ---------------- K3: bitmask fused attn, LDS-staged B, MFMA den -----------
// grid (JC=8, 64) x 256 thr, 2 blocks/CU (~37KB LDS). Per 32-k round:
//   write prefetched B (8KB) to double-buffered LDS, barrier, issue next
//   round's B loads (consumed before next barrier -> vmcnt drain free),
//   w = mask*exp from LDS bitmask (trunc-bf16 + v_perm pack), 16+2 MFMA
//   (2 extra vs all-ones B frag accumulate den == sum of the SAME bf16 w).
__global__ __launch_bounds__(256, 2) void k_attn(
    const unsigned int* __restrict__ bmw,   // bitmask u32 view: [row][256]
    const unsigned short* __restrict__ P,
    const float* __restrict__ f1, const float* __restrict__ f2,
    float* __restrict__ part, float* __restrict__ denp){
  __shared__ unsigned int bs[128*32];           // 16 KB swizzled bitmask tile
  __shared__ float f2s[KCHUNK];                 // 4 KB
  __shared__ float f1s[128];
  __shared__ __align__(16) short Bst[2][4096];  // 2 x 8 KB B double-buffer
  const int tid = threadIdx.x;
  const int wave = tid >> 6, lane = tid & 63;
  const int m = lane & 15, q = lane >> 4;
  const int jc = blockIdx.x;
  const int r0b = blockIdx.y * 128;

  ((float4*)f2s)[tid] = ((const float4*)(f2 + jc*KCHUNK))[tid];
  if(tid < 128) f1s[tid] = f1[r0b + tid];
  {
    const int row = tid >> 1, h16 = (tid & 1) * 16;
    const unsigned int* src = bmw + (size_t)(r0b + row)*256 + jc*32 + h16;
    const int sw = row & 31;
    #pragma unroll
    for(int i=0;i<16;i+=4){
      uint4 v = *(const uint4*)(src + i);
      bs[row*32 + ((h16+i  ) ^ sw)] = v.x;
      bs[row*32 + ((h16+i+1) ^ sw)] = v.y;
      bs[row*32 + ((h16+i+2) ^ sw)] = v.z;
      bs[row*32 + ((h16+i+3) ^ sw)] = v.w;
    }
  }

  const int rg0 = wave*32 + m;
  const unsigned int* bw0 = &bs[rg0*32];
  const unsigned int* bw1 = &bs[(rg0+16)*32];
  const int x0 = rg0 & 31, x1 = (rg0+16) & 31;
  const short8* PB = (const short8*)P + (size_t)jc*ROUNDS*512;
  const int sl0 = (2*wave)*64 + lane, sl1 = sl0 + 64;

  f32x4 acc0[8], acc1[8], accd0 = {0,0,0,0}, accd1 = {0,0,0,0};
  #pragma unroll
  for(int c=0;c<8;c++){ acc0[c] = (f32x4){0,0,0,0}; acc1[c] = (f32x4){0,0,0,0}; }
  const short8 ones = {0x3F80,0x3F80,0x3F80,0x3F80,0x3F80,0x3F80,0x3F80,0x3F80};

  short8 Bp0 = PB[sl0], Bp1 = PB[sl1];
  __syncthreads();                              // bs/f1s/f2s ready
  const float rf1a = f1s[rg0], rf1b = f1s[rg0 + 16];

  auto wc8 = [&](unsigned int bits, float4 fa, float4 fb, float rf1) -> short8 {
    float w[8]; float t;
    #define WE(i, fv)                                      \
      t = rf1 + (fv); t = fmaxf(t, ALPHA*t);               \
      w[i] = (bits & (1u<<(i))) ? __expf(t) : 0.f;
    WE(0,fa.x) WE(1,fa.y) WE(2,fa.z) WE(3,fa.w)
    WE(4,fb.x) WE(5,fb.y) WE(6,fb.z) WE(7,fb.w)
    #undef WE
    union { short8 s; uint4 u; } r;
    #pragma unroll
    for(int i=0;i<4;i++)
      r.u[i] = __builtin_amdgcn_perm(__float_as_uint(w[2*i+1]),
                                     __float_as_uint(w[2*i]), 0x07060302);
    return r.s;
  };

  for(int rd=0; rd<ROUNDS; rd++){
    short8* Bw = (short8*)Bst[rd & 1];
    Bw[sl0] = Bp0; Bw[sl1] = Bp1;
    __syncthreads();
    if(rd+1 < ROUNDS){
      Bp0 = PB[(rd+1)*512 + sl0];
      Bp1 = PB[(rd+1)*512 + sl1];
    }
    unsigned int b0 = (bw0[rd ^ x0] >> (q*8)) & 0xffu;
    unsigned int b1 = (bw1[rd ^ x1] >> (q*8)) & 0xffu;
    float4 fva = *(const float4*)(f2s + rd*32 + q*8);
    float4 fvb = *(const float4*)(f2s + rd*32 + q*8 + 4);
    short8 af0 = wc8(b0, fva, fvb, rf1a);
    short8 af1 = wc8(b1, fva, fvb, rf1b);
    const short8* Br = (const short8*)Bst[rd & 1] + lane;
    #pragma unroll
    for(int c=0;c<8;c++){
      short8 Bf = Br[c*64];
      acc0[c] = __builtin_amdgcn_mfma_f32_16x16x32_bf16(af0, Bf, acc0[c], 0,0,0);
      acc1[c] = __builtin_amdgcn_mfma_f32_16x16x32_bf16(af1, Bf, acc1[c], 0,0,0);
    }
    accd0 = __builtin_amdgcn_mfma_f32_16x16x32_bf16(af0, ones, accd0, 0,0,0);
    accd1 = __builtin_amdgcn_mfma_f32_16x16x32_bf16(af1, ones, accd1, 0,0,0);
    __syncthreads();                            // before overwriting Bst[rd&1]^... next round
  }

  const int r0w = r0b + wave*32;
  if(m == 0){
    #pragma unroll
    for(int reg=0;reg<4;reg++){
      denp[(size_t)jc*N_NODES + r0w + q*4 + reg]      = accd0[reg];
      denp[(size_t)jc*N_NODES + r0w + 16 + q*4 + reg] = accd1[reg];
    }
  }
  // C/D layout: col = c*16 + m, row = q*4 + reg (verified R1-R6)
  float* pp = part + (size_t)jc*N_NODES*OUT_F;
  #pragma unroll
  for(int c=0;c<8;c++){
    #pragma unroll
    for(int reg=0;reg<4;reg++){
      pp[(size_t)(r0w + q*4 + reg)*OUT_F      + c*16 + m] = acc0[c][reg];
      pp[(size_t)(r0w + 16 + q*4 + reg)*OUT_F + c*16 + m] = acc1[c][reg];
    }
  }
}

// ---------------- K4: out = elu(sum(parts)/sum(dens)) ----------------
__global__ __launch_bounds__(256) void k_out(const float* __restrict__ part,
    const float* __restrict__ denp, float* __restrict__ out){
  const int idx = blockIdx.x*256 + threadIdx.x;
  const int r = idx >> 7;
  float v = 0.f, d = 0.f;
  #pragma unroll
  for(int p=0;p<JC;p++){
    v += part[(size_t)p*N_NODES*OUT_F + idx];
    d += denp[(size_t)p*N_NODES + r];
  }
  v /= d;
  out[idx] = v > 0.f ? v : (__expf(v) - 1.f);
}

extern "C" void kernel_launch(void* const* d_in, const int* in_sizes, int n_in,
                              void* d_out, int out_size, void* d_ws, size_t ws_size,
                              hipStream_t stream){
  const float* x   = (const float*)d_in[0];
  const int*   adj = (const int*)d_in[1];
  const float* W   = (const float*)d_in[2];
  const float* a   = (const float*)d_in[3];
  char* ws = (char*)d_ws;
  // ws: [4,6M) P | 6M: f1,f2 | [8,40M) parts | [40M,+256K) dens | [48,56M) bitmask
  unsigned short* P   = (unsigned short*)(ws + (4u<<20));
  float* f1           = (float*)(ws + (6u<<20));
  float* f2           = (float*)(ws + (6u<<20) + (32u<<10));
  float* part         = (float*)(ws + (8u<<20));
  float* denp         = (float*)(ws + (40u<<20));
  unsigned long long* bm = (unsigned long long*)(ws + (48u<<20));
  float* out          = (float*)d_out;

  k_comp<<<2048, 256, 0, stream>>>(adj, bm);
  k_hfp<<<256, 256, 0, stream>>>(x, W, a, f1, f2, P);
  k_attn<<<dim3(JC,64), 256, 0, stream>>>((const unsigned int*)bm, P, f1, f2, part, denp);
  k_out<<<(N_NODES*OUT_F)/256, 256, 0, stream>>>(part, denp, out);
}

// Round 8
// 413.993 us; speedup vs baseline: 1.0774x; 1.0774x over previous
//
#include <hip/hip_runtime.h>

#define N_NODES 8192
#define IN_F 256
#define OUT_F 128
#define ALPHA 0.5f
#define JC 8
#define KCHUNK 1024            // N_NODES / JC
#define ROUNDS 32              // KCHUNK / 32
#define HFP_BLOCKS 256
#define COMP_BLOCKS 2048

using short8 = __attribute__((ext_vector_type(8))) short;
using f32x4  = __attribute__((ext_vector_type(4))) float;

__device__ __forceinline__ unsigned int f2bf(float f){
  unsigned int u = __float_as_uint(f);
  u += 0x7fffu + ((u >> 16) & 1u);   // RNE
  return u >> 16;
}

// ---------------- K1: heterogeneous prep ----------------
// blocks [0,256): h = x@W -> f1,f2,P (compute-bound, no HBM pressure)
// blocks [256,2304): adj -> bitmask, linear stream (HBM-bound)
// The two halves overlap on the machine instead of serializing.
__global__ __launch_bounds__(256) void k_prep(const float* __restrict__ x,
                                              const float* __restrict__ W,
                                              const float* __restrict__ a,
                                              const int* __restrict__ adj,
                                              float* __restrict__ f1,
                                              float* __restrict__ f2,
                                              unsigned short* __restrict__ P,
                                              unsigned long long* __restrict__ bm){
  __shared__ float xs[32*128];           // 16 KB (half-K staging)
  __shared__ unsigned short hl[32*136];  // 8.5 KB padded bf16 h tile
  const int tid = threadIdx.x;

  if(blockIdx.x >= HFP_BLOCKS){
    // ---- compress: wave reads 64 consecutive ints -> one uint64 ----
    const int lane = tid & 63;
    const int wid = ((blockIdx.x - HFP_BLOCKS)*256 + tid) >> 6;
    const int nw = (COMP_BLOCKS*256) >> 6;
    const size_t total = (size_t)N_NODES*N_NODES;
    for(size_t base = (size_t)wid*512; base < total; base += (size_t)nw*512){
      unsigned long long msk[8];
      #pragma unroll
      for(int u=0;u<8;u++){
        int v = adj[base + (size_t)u*64 + lane];
        msk[u] = __ballot(v > 0);
      }
      if(lane < 8){
        unsigned long long v = msk[0];
        #pragma unroll
        for(int u=1;u<8;u++) v = (lane == u) ? msk[u] : v;
        bm[base/64 + lane] = v;
      }
    }
    return;
  }

  // ---- hfp: 32 rows of h in registers; x staged in two 16KB halves ----
  const int r0 = blockIdx.x * 32;
  const int wave = tid >> 6, lane = tid & 63;
  float2 acc[8];
  #pragma unroll
  for(int j=0;j<8;j++){ acc[j].x = 0.f; acc[j].y = 0.f; }
  const float2* Wp = (const float2*)W;       // cols (2l,2l+1) at k*64+l
  for(int half=0; half<2; half++){
    if(half) __syncthreads();
    #pragma unroll
    for(int i=0;i<4;i++){
      int s = tid + i*256;                   // 1024 float4 slots
      int row = s >> 5, c4 = (s & 31)*4;
      ((float4*)xs)[s] = *(const float4*)(x + (size_t)(r0+row)*IN_F + half*128 + c4);
    }
    __syncthreads();
    for(int k4=0;k4<128;k4+=4){
      float4 xq[8];
      #pragma unroll
      for(int j=0;j<8;j++) xq[j] = *(const float4*)&xs[(wave*8+j)*128 + k4];
      #pragma unroll
      for(int kk=0;kk<4;kk++){
        float2 wv = Wp[(size_t)(half*128 + k4 + kk)*64 + lane];
        #pragma unroll
        for(int j=0;j<8;j++){
          float xv = kk==0?xq[j].x : kk==1?xq[j].y : kk==2?xq[j].z : xq[j].w;
          acc[j].x += xv*wv.x; acc[j].y += xv*wv.y;
        }
      }
    }
  }
  // f1/f2
  {
    float2 a1 = ((const float2*)a)[lane];
    float2 a2 = ((const float2*)(a + OUT_F))[lane];
    float s1[8], s2[8];
    #pragma unroll
    for(int j=0;j<8;j++){
      s1[j] = acc[j].x*a1.x + acc[j].y*a1.y;
      s2[j] = acc[j].x*a2.x + acc[j].y*a2.y;
    }
    #pragma unroll
    for(int off=32; off; off>>=1){
      #pragma unroll
      for(int j=0;j<8;j++){
        s1[j] += __shfl_down(s1[j], off);
        s2[j] += __shfl_down(s2[j], off);
      }
    }
    if(lane == 0){
      #pragma unroll
      for(int j=0;j<8;j++){
        f1[r0 + wave*8 + j] = s1[j];
        f2[r0 + wave*8 + j] = s2[j];
      }
    }
  }
  // pack bf16 h -> fragment-major P
  #pragma unroll
  for(int j=0;j<8;j++){
    unsigned int u = f2bf(acc[j].x) | (f2bf(acc[j].y) << 16);
    *(unsigned int*)&hl[(wave*8+j)*136 + 2*lane] = u;
  }
  __syncthreads();
  #pragma unroll
  for(int i=0;i<2;i++){
    int o = tid*2 + i;
    int c = o >> 6, ln = o & 63;
    int q = ln >> 4, n = ln & 15;
    short8 v;
    #pragma unroll
    for(int t=0;t<8;t++) v[t] = (short)hl[(q*8+t)*136 + c*16 + n];
    *(short8*)(P + ((size_t)(blockIdx.x*8 + c)*64 + ln)*8) = v;
  }
}

// ---------------- K2: bitmask fused attn, 64-row blocks, 1 barrier/round ---
// grid (JC=8, 128) = 1024 blocks -> 4 blocks/CU (~28KB LDS). Each wave owns
// one 16-row m-tile. B double-buffered in LDS; single barrier per round.
__global__ __launch_bounds__(256, 4) void k_attn(
    const unsigned int* __restrict__ bmw,   // bitmask u32 view: [row][256]
    const unsigned short* __restrict__ P,
    const float* __restrict__ f1, const float* __restrict__ f2,
    float* __restrict__ part, float* __restrict__ denp){
  __shared__ unsigned int bs[64*32];            // 8 KB swizzled bitmask tile
  __shared__ float f2s[KCHUNK];                 // 4 KB
  __shared__ float f1s[64];
  __shared__ __align__(16) short Bst[2][4096];  // 2 x 8 KB B double-buffer
  const int tid = threadIdx.x;
  const int wave = tid >> 6, lane = tid & 63;
  const int m = lane & 15, q = lane >> 4;
  const int jc = blockIdx.x;
  const int r0b = blockIdx.y * 64;

  ((float4*)f2s)[tid] = ((const float4*)(f2 + jc*KCHUNK))[tid];
  if(tid < 64) f1s[tid] = f1[r0b + tid];
  {
    const int row = tid >> 2, seg = (tid & 3) * 8;
    const unsigned int* src = bmw + (size_t)(r0b + row)*256 + jc*32 + seg;
    const int sw = row & 31;
    #pragma unroll
    for(int i=0;i<8;i+=4){
      uint4 v = *(const uint4*)(src + i);
      bs[row*32 + ((seg+i  ) ^ sw)] = v.x;
      bs[row*32 + ((seg+i+1) ^ sw)] = v.y;
      bs[row*32 + ((seg+i+2) ^ sw)] = v.z;
      bs[row*32 + ((seg+i+3) ^ sw)] = v.w;
    }
  }

  const int rg0 = wave*16 + m;                  // block-local row of this lane
  const int x0 = rg0 & 31;
  const short8* PB = (const short8*)P + (size_t)jc*ROUNDS*512;
  const int sl0 = (2*wave)*64 + lane, sl1 = sl0 + 64;

  f32x4 acc[8], accd = {0,0,0,0};
  #pragma unroll
  for(int c=0;c<8;c++) acc[c] = (f32x4){0,0,0,0};
  const short8 ones = {0x3F80,0x3F80,0x3F80,0x3F80,0x3F80,0x3F80,0x3F80,0x3F80};

  short8 Bp0 = PB[sl0], Bp1 = PB[sl1];
  __syncthreads();                              // bs/f1s/f2s ready
  const float rf1 = f1s[rg0];
  const unsigned int* bw = &bs[rg0*32];

  for(int rd=0; rd<ROUNDS; rd++){
    short8* Bw = (short8*)Bst[rd & 1];
    Bw[sl0] = Bp0; Bw[sl1] = Bp1;
    __syncthreads();                            // single barrier per round
    if(rd+1 < ROUNDS){
      Bp0 = PB[(rd+1)*512 + sl0];
      Bp1 = PB[(rd+1)*512 + sl1];
    }
    unsigned int b = (bw[rd ^ x0] >> (q*8)) & 0xffu;
    float4 fa = *(const float4*)(f2s + rd*32 + q*8);
    float4 fb = *(const float4*)(f2s + rd*32 + q*8 + 4);
    short8 af;
    {
      float w[8]; float t;
      #define WE(i, fv)                                    \
        t = rf1 + (fv); t = fmaxf(t, ALPHA*t);             \
        w[i] = (b & (1u<<(i))) ? __expf(t) : 0.f;
      WE(0,fa.x) WE(1,fa.y) WE(2,fa.z) WE(3,fa.w)
      WE(4,fb.x) WE(5,fb.y) WE(6,fb.z) WE(7,fb.w)
      #undef WE
      union { short8 s; uint4 u; } r;
      #pragma unroll
      for(int i=0;i<4;i++)
        r.u[i] = __builtin_amdgcn_perm(__float_as_uint(w[2*i+1]),
                                       __float_as_uint(w[2*i]), 0x07060302);
      af = r.s;
    }
    const short8* Br = (const short8*)Bst[rd & 1] + lane;
    #pragma unroll
    for(int c=0;c<8;c++)
      acc[c] = __builtin_amdgcn_mfma_f32_16x16x32_bf16(af, Br[c*64], acc[c], 0,0,0);
    accd = __builtin_amdgcn_mfma_f32_16x16x32_bf16(af, ones, accd, 0,0,0);
  }

  const int r0w = r0b + wave*16;
  if(m == 0){
    #pragma unroll
    for(int reg=0;reg<4;reg++)
      denp[(size_t)jc*N_NODES + r0w + q*4 + reg] = accd[reg];
  }
  // C/D layout: col = c*16 + m, row = q*4 + reg (verified R1-R7)
  float* pp = part + (size_t)jc*N_NODES*OUT_F;
  #pragma unroll
  for(int c=0;c<8;c++){
    #pragma unroll
    for(int reg=0;reg<4;reg++)
      pp[(size_t)(r0w + q*4 + reg)*OUT_F + c*16 + m] = acc[c][reg];
  }
}

// ---------------- K3: out = elu(sum(parts)/sum(dens)), float4 --------------
__global__ __launch_bounds__(256) void k_out(const float* __restrict__ part,
    const float* __restrict__ denp, float* __restrict__ out){
  const int i4 = blockIdx.x*256 + threadIdx.x;   // float4 index
  const int r = i4 >> 5;                         // 32 float4 per row
  float4 v = {0,0,0,0};
  float d = 0.f;
  #pragma unroll
  for(int p=0;p<JC;p++){
    float4 t = ((const float4*)(part + (size_t)p*N_NODES*OUT_F))[i4];
    v.x += t.x; v.y += t.y; v.z += t.z; v.w += t.w;
    d += denp[(size_t)p*N_NODES + r];
  }
  float inv = 1.f / d;
  v.x *= inv; v.y *= inv; v.z *= inv; v.w *= inv;
  v.x = v.x > 0.f ? v.x : (__expf(v.x) - 1.f);
  v.y = v.y > 0.f ? v.y : (__expf(v.y) - 1.f);
  v.z = v.z > 0.f ? v.z : (__expf(v.z) - 1.f);
  v.w = v.w > 0.f ? v.w : (__expf(v.w) - 1.f);
  ((float4*)out)[i4] = v;
}

extern "C" void kernel_launch(void* const* d_in, const int* in_sizes, int n_in,
                              void* d_out, int out_size, void* d_ws, size_t ws_size,
                              hipStream_t stream){
  const float* x   = (const float*)d_in[0];
  const int*   adj = (const int*)d_in[1];
  const float* W   = (const float*)d_in[2];
  const float* a   = (const float*)d_in[3];
  char* ws = (char*)d_ws;
  // ws: [4,6M) P | 6M: f1,f2 | [8,40M) parts | [40M,+256K) dens | [48,56M) bitmask
  unsigned short* P   = (unsigned short*)(ws + (4u<<20));
  float* f1           = (float*)(ws + (6u<<20));
  float* f2           = (float*)(ws + (6u<<20) + (32u<<10));
  float* part         = (float*)(ws + (8u<<20));
  float* denp         = (float*)(ws + (40u<<20));
  unsigned long long* bm = (unsigned long long*)(ws + (48u<<20));
  float* out          = (float*)d_out;

  k_prep<<<HFP_BLOCKS + COMP_BLOCKS, 256, 0, stream>>>(x, W, a, adj, f1, f2, P, bm);
  k_attn<<<dim3(JC,128), 256, 0, stream>>>((const unsigned int*)bm, P, f1, f2, part, denp);
  k_out<<<(N_NODES*OUT_F/4)/256, 256, 0, stream>>>(part, denp, out);
}

// Round 9
// 412.198 us; speedup vs baseline: 1.0821x; 1.0044x over previous
//
#include <hip/hip_runtime.h>

#define N_NODES 8192
#define IN_F 256
#define OUT_F 128
#define ALPHA 0.5f
#define JC 8
#define KCHUNK 1024            // N_NODES / JC
#define ROUNDS 32              // KCHUNK / 32
#define HFP_BLOCKS 256
#define COMP_BLOCKS 2048

using short8 = __attribute__((ext_vector_type(8))) short;
using f32x4  = __attribute__((ext_vector_type(4))) float;

__device__ __forceinline__ unsigned int f2bf(float f){
  unsigned int u = __float_as_uint(f);
  u += 0x7fffu + ((u >> 16) & 1u);   // RNE
  return u >> 16;
}

// ---------------- K1: heterogeneous prep ----------------
// blocks [0,256): h = x@W -> f1,f2,P (compute-bound, no HBM pressure)
// blocks [256,2304): adj -> bitmask, linear stream (HBM-bound). Overlapped.
__global__ __launch_bounds__(256) void k_prep(const float* __restrict__ x,
                                              const float* __restrict__ W,
                                              const float* __restrict__ a,
                                              const int* __restrict__ adj,
                                              float* __restrict__ f1,
                                              float* __restrict__ f2,
                                              unsigned short* __restrict__ P,
                                              unsigned long long* __restrict__ bm){
  __shared__ float xs[32*128];           // 16 KB (half-K staging)
  __shared__ unsigned short hl[32*136];  // 8.5 KB padded bf16 h tile
  const int tid = threadIdx.x;

  if(blockIdx.x >= HFP_BLOCKS){
    // ---- compress: wave reads 64 consecutive ints -> one uint64 ----
    const int lane = tid & 63;
    const int wid = ((blockIdx.x - HFP_BLOCKS)*256 + tid) >> 6;
    const int nw = (COMP_BLOCKS*256) >> 6;
    const size_t total = (size_t)N_NODES*N_NODES;
    for(size_t base = (size_t)wid*512; base < total; base += (size_t)nw*512){
      unsigned long long msk[8];
      #pragma unroll
      for(int u=0;u<8;u++){
        int v = adj[base + (size_t)u*64 + lane];
        msk[u] = __ballot(v > 0);
      }
      if(lane < 8){
        unsigned long long v = msk[0];
        #pragma unroll
        for(int u=1;u<8;u++) v = (lane == u) ? msk[u] : v;
        bm[base/64 + lane] = v;
      }
    }
    return;
  }

  // ---- hfp: 32 rows of h in registers; x staged in two 16KB halves ----
  const int r0 = blockIdx.x * 32;
  const int wave = tid >> 6, lane = tid & 63;
  float2 acc[8];
  #pragma unroll
  for(int j=0;j<8;j++){ acc[j].x = 0.f; acc[j].y = 0.f; }
  const float2* Wp = (const float2*)W;       // cols (2l,2l+1) at k*64+l
  for(int half=0; half<2; half++){
    if(half) __syncthreads();
    #pragma unroll
    for(int i=0;i<4;i++){
      int s = tid + i*256;                   // 1024 float4 slots
      int row = s >> 5, c4 = (s & 31)*4;
      ((float4*)xs)[s] = *(const float4*)(x + (size_t)(r0+row)*IN_F + half*128 + c4);
    }
    __syncthreads();
    for(int k4=0;k4<128;k4+=4){
      float4 xq[8];
      #pragma unroll
      for(int j=0;j<8;j++) xq[j] = *(const float4*)&xs[(wave*8+j)*128 + k4];
      #pragma unroll
      for(int kk=0;kk<4;kk++){
        float2 wv = Wp[(size_t)(half*128 + k4 + kk)*64 + lane];
        #pragma unroll
        for(int j=0;j<8;j++){
          float xv = kk==0?xq[j].x : kk==1?xq[j].y : kk==2?xq[j].z : xq[j].w;
          acc[j].x += xv*wv.x; acc[j].y += xv*wv.y;
        }
      }
    }
  }
  // f1/f2
  {
    float2 a1 = ((const float2*)a)[lane];
    float2 a2 = ((const float2*)(a + OUT_F))[lane];
    float s1[8], s2[8];
    #pragma unroll
    for(int j=0;j<8;j++){
      s1[j] = acc[j].x*a1.x + acc[j].y*a1.y;
      s2[j] = acc[j].x*a2.x + acc[j].y*a2.y;
    }
    #pragma unroll
    for(int off=32; off; off>>=1){
      #pragma unroll
      for(int j=0;j<8;j++){
        s1[j] += __shfl_down(s1[j], off);
        s2[j] += __shfl_down(s2[j], off);
      }
    }
    if(lane == 0){
      #pragma unroll
      for(int j=0;j<8;j++){
        f1[r0 + wave*8 + j] = s1[j];
        f2[r0 + wave*8 + j] = s2[j];
      }
    }
  }
  // pack bf16 h -> fragment-major P
  #pragma unroll
  for(int j=0;j<8;j++){
    unsigned int u = f2bf(acc[j].x) | (f2bf(acc[j].y) << 16);
    *(unsigned int*)&hl[(wave*8+j)*136 + 2*lane] = u;
  }
  __syncthreads();
  #pragma unroll
  for(int i=0;i<2;i++){
    int o = tid*2 + i;
    int c = o >> 6, ln = o & 63;
    int q = ln >> 4, n = ln & 15;
    short8 v;
    #pragma unroll
    for(int t=0;t<8;t++) v[t] = (short)hl[(q*8+t)*136 + c*16 + n];
    *(short8*)(P + ((size_t)(blockIdx.x*8 + c)*64 + ln)*8) = v;
  }
}

// ---------------- K2: bitmask fused attn, 32 rows/wave, 1 barrier/round ----
// grid (JC=8, 64) = 512 blocks (2/CU), block = 4 waves x 32 rows = 128 rows.
// Doubling rows/wave halves per-CU B-fragment LDS duplication (the R8
// bottleneck: 32 -> ~17us LDS-pipe). B double-buffered in LDS, single
// barrier per round (write rd+1 goes to the other buffer; reads of rd are
// in-registers before barrier rd -> safe).
__global__ __launch_bounds__(256, 2) void k_attn(
    const unsigned int* __restrict__ bmw,   // bitmask u32 view: [row][256]
    const unsigned short* __restrict__ P,
    const float* __restrict__ f1, const float* __restrict__ f2,
    float* __restrict__ part, float* __restrict__ denp){
  __shared__ unsigned int bs[128*32];           // 16 KB swizzled bitmask tile
  __shared__ float f2s[KCHUNK];                 // 4 KB
  __shared__ float f1s[128];
  __shared__ __align__(16) short Bst[2][4096];  // 2 x 8 KB B double-buffer
  const int tid = threadIdx.x;
  const int wave = tid >> 6, lane = tid & 63;
  const int m = lane & 15, q = lane >> 4;
  const int jc = blockIdx.x;
  const int r0b = blockIdx.y * 128;

  ((float4*)f2s)[tid] = ((const float4*)(f2 + jc*KCHUNK))[tid];
  if(tid < 128) f1s[tid] = f1[r0b + tid];
  {
    const int row = tid >> 1, h16 = (tid & 1) * 16;
    const unsigned int* src = bmw + (size_t)(r0b + row)*256 + jc*32 + h16;
    const int sw = row & 31;
    #pragma unroll
    for(int i=0;i<16;i+=4){
      uint4 v = *(const uint4*)(src + i);
      bs[row*32 + ((h16+i  ) ^ sw)] = v.x;
      bs[row*32 + ((h16+i+1) ^ sw)] = v.y;
      bs[row*32 + ((h16+i+2) ^ sw)] = v.z;
      bs[row*32 + ((h16+i+3) ^ sw)] = v.w;
    }
  }

  const int rg0 = wave*32 + m;                  // lane's rows: rg0, rg0+16
  const int x0 = rg0 & 31, x1 = (rg0+16) & 31;
  const short8* PB = (const short8*)P + (size_t)jc*ROUNDS*512;
  const int sl0 = (2*wave)*64 + lane, sl1 = sl0 + 64;

  f32x4 acc0[8], acc1[8], accd0 = {0,0,0,0}, accd1 = {0,0,0,0};
  #pragma unroll
  for(int c=0;c<8;c++){ acc0[c] = (f32x4){0,0,0,0}; acc1[c] = (f32x4){0,0,0,0}; }
  const short8 ones = {0x3F80,0x3F80,0x3F80,0x3F80,0x3F80,0x3F80,0x3F80,0x3F80};

  short8 Bp0 = PB[sl0], Bp1 = PB[sl1];
  __syncthreads();                              // bs/f1s/f2s ready
  const float rf1a = f1s[rg0], rf1b = f1s[rg0 + 16];
  const unsigned int* bw0 = &bs[rg0*32];
  const unsigned int* bw1 = &bs[(rg0+16)*32];

  auto wc8 = [&](unsigned int bits, float4 fa, float4 fb, float rf1) -> short8 {
    float w[8]; float t;
    #define WE(i, fv)                                      \
      t = rf1 + (fv); t = fmaxf(t, ALPHA*t);               \
      w[i] = (bits & (1u<<(i))) ? __expf(t) : 0.f;
    WE(0,fa.x) WE(1,fa.y) WE(2,fa.z) WE(3,fa.w)
    WE(4,fb.x) WE(5,fb.y) WE(6,fb.z) WE(7,fb.w)
    #undef WE
    union { short8 s; uint4 u; } r;
    #pragma unroll
    for(int i=0;i<4;i++)
      r.u[i] = __builtin_amdgcn_perm(__float_as_uint(w[2*i+1]),
                                     __float_as_uint(w[2*i]), 0x07060302);
    return r.s;
  };

  for(int rd=0; rd<ROUNDS; rd++){
    short8* Bw = (short8*)Bst[rd & 1];
    Bw[sl0] = Bp0; Bw[sl1] = Bp1;
    __syncthreads();                            // single barrier per round
    if(rd+1 < ROUNDS){
      Bp0 = PB[(rd+1)*512 + sl0];
      Bp1 = PB[(rd+1)*512 + sl1];
    }
    unsigned int b0 = (bw0[rd ^ x0] >> (q*8)) & 0xffu;
    unsigned int b1 = (bw1[rd ^ x1] >> (q*8)) & 0xffu;
    float4 fa = *(const float4*)(f2s + rd*32 + q*8);
    float4 fb = *(const float4*)(f2s + rd*32 + q*8 + 4);
    short8 af0 = wc8(b0, fa, fb, rf1a);
    short8 af1 = wc8(b1, fa, fb, rf1b);
    const short8* Br = (const short8*)Bst[rd & 1] + lane;
    #pragma unroll
    for(int c=0;c<8;c++){
      short8 Bf = Br[c*64];
      acc0[c] = __builtin_amdgcn_mfma_f32_16x16x32_bf16(af0, Bf, acc0[c], 0,0,0);
      acc1[c] = __builtin_amdgcn_mfma_f32_16x16x32_bf16(af1, Bf, acc1[c], 0,0,0);
    }
    accd0 = __builtin_amdgcn_mfma_f32_16x16x32_bf16(af0, ones, accd0, 0,0,0);
    accd1 = __builtin_amdgcn_mfma_f32_16x16x32_bf16(af1, ones, accd1, 0,0,0);
  }

  const int r0w = r0b + wave*32;
  if(m == 0){
    #pragma unroll
    for(int reg=0;reg<4;reg++){
      denp[(size_t)jc*N_NODES + r0w + q*4 + reg]      = accd0[reg];
      denp[(size_t)jc*N_NODES + r0w + 16 + q*4 + reg] = accd1[reg];
    }
  }
  // C/D layout: col = c*16 + m, row = q*4 + reg (verified R1-R8)
  float* pp = part + (size_t)jc*N_NODES*OUT_F;
  #pragma unroll
  for(int c=0;c<8;c++){
    #pragma unroll
    for(int reg=0;reg<4;reg++){
      pp[(size_t)(r0w + q*4 + reg)*OUT_F      + c*16 + m] = acc0[c][reg];
      pp[(size_t)(r0w + 16 + q*4 + reg)*OUT_F + c*16 + m] = acc1[c][reg];
    }
  }
}

// ---------------- K3: out = elu(sum(parts)/sum(dens)), float4 --------------
__global__ __launch_bounds__(256) void k_out(const float* __restrict__ part,
    const float* __restrict__ denp, float* __restrict__ out){
  const int i4 = blockIdx.x*256 + threadIdx.x;   // float4 index
  const int r = i4 >> 5;                         // 32 float4 per row
  float4 v = {0,0,0,0};
  float d = 0.f;
  #pragma unroll
  for(int p=0;p<JC;p++){
    float4 t = ((const float4*)(part + (size_t)p*N_NODES*OUT_F))[i4];
    v.x += t.x; v.y += t.y; v.z += t.z; v.w += t.w;
    d += denp[(size_t)p*N_NODES + r];
  }
  float inv = 1.f / d;
  v.x *= inv; v.y *= inv; v.z *= inv; v.w *= inv;
  v.x = v.x > 0.f ? v.x : (__expf(v.x) - 1.f);
  v.y = v.y > 0.f ? v.y : (__expf(v.y) - 1.f);
  v.z = v.z > 0.f ? v.z : (__expf(v.z) - 1.f);
  v.w = v.w > 0.f ? v.w : (__expf(v.w) - 1.f);
  ((float4*)out)[i4] = v;
}

extern "C" void kernel_launch(void* const* d_in, const int* in_sizes, int n_in,
                              void* d_out, int out_size, void* d_ws, size_t ws_size,
                              hipStream_t stream){
  const float* x   = (const float*)d_in[0];
  const int*   adj = (const int*)d_in[1];
  const float* W   = (const float*)d_in[2];
  const float* a   = (const float*)d_in[3];
  char* ws = (char*)d_ws;
  // ws: [4,6M) P | 6M: f1,f2 | [8,40M) parts | [40M,+256K) dens | [48,56M) bitmask
  unsigned short* P   = (unsigned short*)(ws + (4u<<20));
  float* f1           = (float*)(ws + (6u<<20));
  float* f2           = (float*)(ws + (6u<<20) + (32u<<10));
  float* part         = (float*)(ws + (8u<<20));
  float* denp         = (float*)(ws + (40u<<20));
  unsigned long long* bm = (unsigned long long*)(ws + (48u<<20));
  float* out          = (float*)d_out;

  k_prep<<<HFP_BLOCKS + COMP_BLOCKS, 256, 0, stream>>>(x, W, a, adj, f1, f2, P, bm);
  k_attn<<<dim3(JC,64), 256, 0, stream>>>((const unsigned int*)bm, P, f1, f2, part, denp);
  k_out<<<(N_NODES*OUT_F/4)/256, 256, 0, stream>>>(part, denp, out);
}